// Round 11
// baseline (6667.633 us; speedup 1.0000x reference)
//
#include <hip/hip_runtime.h>
#include <hip/hip_bf16.h>
#include <math.h>

using bf16 = __hip_bfloat16;

#define BB 1024
#define TT 13
#define YY 188
#define HH 512
#define GG 1536
#define YP 192
#define DS 13
#define NT 96   // GG/16 B-tiles along the gate dimension

typedef __bf16 bf16x8 __attribute__((ext_vector_type(8)));
typedef float f32x4 __attribute__((ext_vector_type(4)));
typedef float f4 __attribute__((ext_vector_type(4)));

__device__ __forceinline__ float sigf(float x) { return 1.f / (1.f + expf(-x)); }
__device__ __forceinline__ bf16x8 ldf(const bf16* p) {
  return *reinterpret_cast<const bf16x8*>(p);
}
__device__ __forceinline__ f32x4 mf(bf16x8 a, bf16x8 b, f32x4 c) {
  return __builtin_amdgcn_mfma_f32_16x16x32_bf16(a, b, c, 0, 0, 0);
}
__device__ __forceinline__ void split2(float v, bf16& hi, bf16& lo) {
  hi = __float2bfloat16(v);
  lo = __float2bfloat16(v - __bfloat162float(hi));
}

// Per-phase cell table (<=13 independent (d,t) cells), passed by value.
struct GruPhase {
  int ncells;
  int zmask;             // bit c: t==0 (skip gh GEMM, h_prev = 0)
  unsigned a1off[13];    // A1 element offset per cell
  unsigned hoff[13];     // h_prev element offset per cell
  unsigned ooff[13];     // h_out  element offset per cell
};

// ---------------------------------------------------------------------------
// Swizzle a row-major (Nsrc x Ksrc) fp32 weight into KT-MAJOR MFMA B-frag
// order, split hi/lo, zero-padded. Tile (kt,nt) at elem (kt*NT + nt)*512;
// lane l holds W[nt*16+(l&15)][kt*32+(l>>4)*8+j], j=0..7 contiguous.
// ---------------------------------------------------------------------------
__global__ void k_swz2(const float* __restrict__ src, bf16* __restrict__ dhi,
                       bf16* __restrict__ dlo, int Nsrc, int Ksrc) {
  int idx = blockIdx.x * 256 + threadIdx.x;   // ((kt*NT+nt), lane)
  int l = idx & 63;
  int ktnt = idx >> 6;
  int nt = ktnt % NT, kt = ktnt / NT;
  int n = nt * 16 + (l & 15);
  int k0 = kt * 32 + (l >> 4) * 8;
#pragma unroll
  for (int j = 0; j < 8; ++j) {
    int k = k0 + j;
    float v = (n < Nsrc && k < Ksrc) ? src[(size_t)n * Ksrc + k] : 0.f;
    bf16 h, lo;
    split2(v, h, lo);
    dhi[(size_t)idx * 8 + j] = h;
    dlo[(size_t)idx * 8 + j] = lo;
  }
}

// Setup: 26-slot hi/lo token buffers (s<13: x[:,s,:]; s>=13: y_{s-13}), plus
// fp32 residual seeded with x[:,12,:].
__global__ void k_setup(const float* __restrict__ x, bf16* __restrict__ th,
                        bf16* __restrict__ tl, float* __restrict__ res) {
  int idx = blockIdx.x * 256 + threadIdx.x;
  const int total = 26 * BB * YP;
  if (idx < total) {
    int k = idx % YP;
    int b = (idx / YP) % BB;
    int s = idx / (YP * BB);
    float v = 0.f;
    if (s < TT && k < YY) v = x[((size_t)b * TT + s) * YY + k];
    bf16 h, lo;
    split2(v, h, lo);
    th[idx] = h; tl[idx] = lo;
  }
  if (idx < BB * YY) {
    int yy = idx % YY;
    int b = idx / YY;
    res[idx] = x[((size_t)b * TT + 12) * YY + yy];
  }
}

// ---------------------------------------------------------------------------
// Phase-batched GRU step v3: 128 rows x 64 h-cols per block, waves 2x2
// (each wave 64r x 32c x 3 gates) — waves split cols so each reads only its
// half of the LDS B-slice (r10 broadcast the same slice to all 4 waves and
// was LDS/VMEM-bound at 26% MfmaUtil; this doubles MFMA per staged/read byte).
// Per kt: stage 24 KiB B (3g x 4nt x hi/lo), dbuf; per wave 8 A-frag global
// loads + 12 ds_read_b128 + 72 MFMA.
// ---------------------------------------------------------------------------
template <int KT1>
__global__ __launch_bounds__(256) void gru3(
    const bf16* __restrict__ a1h, const bf16* __restrict__ a1l, int lda1,
    const bf16* __restrict__ W1h, const bf16* __restrict__ W1l,
    const float* __restrict__ b1,
    const bf16* __restrict__ hbh, const bf16* __restrict__ hbl,
    const bf16* __restrict__ W2h, const bf16* __restrict__ W2l,
    const float* __restrict__ b2,
    bf16* __restrict__ obh, bf16* __restrict__ obl,
    GruPhase ph)
{
  __shared__ __align__(16) __bf16 Bl[2][24][512];   // 48 KiB double-buffer
  const int tid = threadIdx.x;
  const int w = tid >> 6, l = tid & 63;
  const int lr = l & 15, lq = l >> 4, kq = lq * 8;
  const int wr = w >> 1, wc = w & 1;
  const int cell = blockIdx.y >> 3, rt = blockIdx.y & 7;
  const int cg = blockIdx.x;                // 8 col-groups of 64 h-cols
  const int m0 = rt * 128 + wr * 64;        // wave's 64-row base
  const bf16* A1h = a1h + ph.a1off[cell];
  const bf16* A1l = a1l + ph.a1off[cell];
  const bf16* HPh = hbh + ph.hoff[cell];
  const bf16* HPl = hbl + ph.hoff[cell];
  bf16* HOh = obh + ph.ooff[cell];
  bf16* HOl = obl + ph.ooff[cell];
  const int zero_h = (ph.zmask >> cell) & 1;

  const f32x4 vzero = {0.f, 0.f, 0.f, 0.f};
  f32x4 arz[4][2][2];            // [rf][r|z][ntl] : xg+gh joint accumulation
  f32x4 axn[4][2], ahn[4][2];    // n-gate parts kept separate
#pragma unroll
  for (int rf = 0; rf < 4; ++rf)
#pragma unroll
    for (int ntl = 0; ntl < 2; ++ntl) {
      arz[rf][0][ntl] = vzero; arz[rf][1][ntl] = vzero;
      axn[rf][ntl] = vzero; ahn[rf][ntl] = vzero;
    }

  // stage the 24 KiB B-slice (24 x 1 KiB tiles, order (g, j, hl)) for ktW
  auto stage = [&](const bf16* Wh, const bf16* Wl2, int ktW, int buf) {
#pragma unroll
    for (int r = 0; r < 6; ++r) {
      int u = r * 256 + tid;     // 16B-unit index in [0, 1536)
      int t2 = u >> 6;           // tile 0..23
      int ui = u & 63;
      int hl = t2 & 1;
      int bn = t2 >> 1;          // (g, j): g = bn>>2, j = bn&3
      int ntg = (bn >> 2) * 32 + cg * 4 + (bn & 3);
      const bf16* src = (hl ? Wl2 : Wh) + ((size_t)(ktW * NT + ntg) * 64 + ui) * 8;
      *(bf16x8*)(&Bl[buf][t2][ui * 8]) = ldf(src);
    }
  };
  // one kt of MFMA from LDS buffer `buf`; n-gate accumulates into `an`
  auto compute = [&](const bf16* Ah, const bf16* Al, int lda, int ktA, int buf,
                     f32x4 (&an)[4][2]) {
    bf16x8 a[4][2];
#pragma unroll
    for (int rf = 0; rf < 4; ++rf) {
      const size_t ao = (size_t)(m0 + rf * 16 + lr) * lda + ktA * 32 + kq;
      a[rf][0] = ldf(Ah + ao);
      a[rf][1] = ldf(Al + ao);
    }
#pragma unroll
    for (int g = 0; g < 3; ++g)
#pragma unroll
      for (int ntl = 0; ntl < 2; ++ntl) {
        int t2 = (g * 4 + wc * 2 + ntl) * 2;
        bf16x8 bh  = *(const bf16x8*)(&Bl[buf][t2][l * 8]);
        bf16x8 blo = *(const bf16x8*)(&Bl[buf][t2 + 1][l * 8]);
#pragma unroll
        for (int rf = 0; rf < 4; ++rf) {
          if (g < 2)
            arz[rf][g][ntl] = mf(a[rf][0], blo, mf(a[rf][1], bh,
                                 mf(a[rf][0], bh, arz[rf][g][ntl])));
          else
            an[rf][ntl] = mf(a[rf][0], blo, mf(a[rf][1], bh,
                             mf(a[rf][0], bh, an[rf][ntl])));
        }
      }
  };

  // ---- pass 1: xg over KT1 kts (A = A1)
  stage(W1h, W1l, 0, 0);
  __syncthreads();
  for (int kt = 0; kt < KT1; ++kt) {
    const int buf = kt & 1;
    if (kt + 1 < KT1) stage(W1h, W1l, kt + 1, buf ^ 1);
    else if (!zero_h) stage(W2h, W2l, 0, buf ^ 1);
    compute(A1h, A1l, lda1, kt, buf, axn);
    __syncthreads();
  }
  // ---- pass 2: gh over 16 kts (A = h_prev)
  if (!zero_h) {
    for (int kt = 0; kt < 16; ++kt) {
      const int buf = (KT1 + kt) & 1;
      if (kt + 1 < 16) stage(W2h, W2l, kt + 1, buf ^ 1);
      compute(HPh, HPl, HH, kt, buf, ahn);
      __syncthreads();
    }
  }

  // ---- epilogue: gates + h update; h_prev = hi+lo reconstruction
#pragma unroll
  for (int ntl = 0; ntl < 2; ++ntl) {
    const int col = cg * 64 + wc * 32 + ntl * 16 + lr;
    const float bx0 = b1[col], bx1 = b1[col + HH], bx2 = b1[col + 2 * HH];
    const float bh0 = b2[col], bh1 = b2[col + HH], bh2 = b2[col + 2 * HH];
#pragma unroll
    for (int rf = 0; rf < 4; ++rf)
#pragma unroll
      for (int i = 0; i < 4; ++i) {
        const int row = m0 + rf * 16 + lq * 4 + i;
        const float rr = sigf(arz[rf][0][ntl][i] + bx0 + bh0);
        const float zz = sigf(arz[rf][1][ntl][i] + bx1 + bh1);
        const float nn = tanhf(axn[rf][ntl][i] + bx2 + rr * (ahn[rf][ntl][i] + bh2));
        float hp = 0.f;
        const size_t hidx = (size_t)row * HH + col;
        if (!zero_h)
          hp = __bfloat162float(HPh[hidx]) + __bfloat162float(HPl[hidx]);
        const float hn = (1.f - zz) * nn + zz * hp;
        bf16 sh, sl;
        split2(hn, sh, sl);
        HOh[hidx] = sh;
        HOl[hidx] = sl;
      }
  }
}

// ---------------------------------------------------------------------------
// Output projection, last timestep only (fp32 VALU):
// o = relu(h1) @ W_out^T + b_out + res; res <- o; d_out[:,d,:] <- o (fp32);
// token slot 13+d <- split-bf16(o).  h1 comes in as hi/lo bf16.
// ---------------------------------------------------------------------------
__global__ __launch_bounds__(256) void out_v(
    const bf16* __restrict__ h1h, const bf16* __restrict__ h1l,
    const float* __restrict__ Wo,
    const float* __restrict__ bo,
    float* __restrict__ res,
    bf16* __restrict__ yh, bf16* __restrict__ yl,
    float* __restrict__ outp,
    int d)
{
  int idx = blockIdx.x * 256 + threadIdx.x;
  if (idx >= BB * YY) return;
  int col = idx % YY, row = idx / YY;
  const bf16* hrh = h1h + (size_t)row * HH;
  const bf16* hrl = h1l + (size_t)row * HH;
  const float* wr = Wo + (size_t)col * HH;
  float acc = 0.f;
#pragma unroll 2
  for (int k = 0; k < HH; k += 8) {
    bf16x8 hh = ldf(hrh + k);
    bf16x8 hl = ldf(hrl + k);
    f4 w0 = *(const f4*)&wr[k];
    f4 w1 = *(const f4*)&wr[k + 4];
#pragma unroll
    for (int j = 0; j < 4; ++j) {
      float hv0 = (float)hh[j] + (float)hl[j];
      float hv1 = (float)hh[j + 4] + (float)hl[j + 4];
      acc = fmaf(fmaxf(hv0, 0.f), w0[j], acc);
      acc = fmaf(fmaxf(hv1, 0.f), w1[j], acc);
    }
  }
  float o = acc + bo[col] + res[idx];
  res[idx] = o;
  outp[((size_t)row * DS + d) * YY + col] = o;
  bf16 sh, sl;
  split2(o, sh, sl);
  yh[(size_t)row * YP + col] = sh;
  yl[(size_t)row * YP + col] = sl;
}

extern "C" void kernel_launch(void* const* d_in, const int* in_sizes, int n_in,
                              void* d_out, int out_size, void* d_ws, size_t ws_size,
                              hipStream_t stream)
{
  // role mapping insurance (dict-order signature, greedy fallback)
  static const int sig_dict[11] = {2501632, 288768, 786432, 1536, 1536,
                                   786432, 786432, 1536, 1536, 96256, 188};
  int map[11];
  bool dict_ok = (n_in == 11);
  if (dict_ok)
    for (int r = 0; r < 11; ++r)
      if (in_sizes[r] != sig_dict[r]) { dict_ok = false; break; }
  if (dict_ok) { for (int r = 0; r < 11; ++r) map[r] = r; }
  else {
    bool used[16] = {};
    for (int r = 0; r < 11; ++r) {
      map[r] = r < n_in ? r : 0;
      for (int i = 0; i < n_in && i < 16; ++i)
        if (!used[i] && in_sizes[i] == sig_dict[r]) { map[r] = i; used[i] = true; break; }
    }
  }
  const float* x     = (const float*)d_in[map[0]];
  const float* W_ih0 = (const float*)d_in[map[1]];
  const float* W_hh0 = (const float*)d_in[map[2]];
  const float* b_ih0 = (const float*)d_in[map[3]];
  const float* b_hh0 = (const float*)d_in[map[4]];
  const float* W_ih1 = (const float*)d_in[map[5]];
  const float* W_hh1 = (const float*)d_in[map[6]];
  const float* b_ih1 = (const float*)d_in[map[7]];
  const float* b_hh1 = (const float*)d_in[map[8]];
  const float* W_out = (const float*)d_in[map[9]];
  const float* b_out = (const float*)d_in[map[10]];
  float* outp = (float*)d_out;

  // Schedule: skew-1 (25 phases, 13 h-slots) if workspace allows, else skew-2.
  const int S    = (ws_size >= (size_t)160 << 20) ? 13 : 7;
  const int SKEW = (S == 13) ? 1 : 2;
  const int NPH  = 12 * SKEW + 13;

  char* p = (char*)d_ws;
  auto alloc = [&](size_t bytes) { char* q = p; p += (bytes + 255) & ~(size_t)255; return q; };
  bf16* tokh = (bf16*)alloc((size_t)26 * BB * YP * 2);
  bf16* tokl = (bf16*)alloc((size_t)26 * BB * YP * 2);
  bf16* W0h  = (bf16*)alloc((size_t)GG * YP * 2);
  bf16* W0l  = (bf16*)alloc((size_t)GG * YP * 2);
  bf16* Wh0h = (bf16*)alloc((size_t)GG * HH * 2);
  bf16* Wh0l = (bf16*)alloc((size_t)GG * HH * 2);
  bf16* Wi1h = (bf16*)alloc((size_t)GG * HH * 2);
  bf16* Wi1l = (bf16*)alloc((size_t)GG * HH * 2);
  bf16* Wh1h = (bf16*)alloc((size_t)GG * HH * 2);
  bf16* Wh1l = (bf16*)alloc((size_t)GG * HH * 2);
  bf16* h0h = (bf16*)alloc((size_t)2 * S * BB * HH * 2);  // parity x slot
  bf16* h0l = (bf16*)alloc((size_t)2 * S * BB * HH * 2);
  bf16* h1h = (bf16*)alloc((size_t)2 * S * BB * HH * 2);
  bf16* h1l = (bf16*)alloc((size_t)2 * S * BB * HH * 2);
  float* res = (float*)alloc((size_t)BB * YY * 4);

  k_setup<<<(26 * BB * YP + 255) / 256, 256, 0, stream>>>(x, tokh, tokl, res);
  k_swz2<<<NT * (YP / 32) * 64 / 256, 256, 0, stream>>>(W_ih0, W0h, W0l, GG, YY);
  k_swz2<<<NT * (HH / 32) * 64 / 256, 256, 0, stream>>>(W_hh0, Wh0h, Wh0l, GG, HH);
  k_swz2<<<NT * (HH / 32) * 64 / 256, 256, 0, stream>>>(W_ih1, Wi1h, Wi1l, GG, HH);
  k_swz2<<<NT * (HH / 32) * 64 / 256, 256, 0, stream>>>(W_hh1, Wh1h, Wh1l, GG, HH);

  // Diagonal wavefront: phase(d,t) = t + SKEW*d. Cells in phase p read
  // h-parity (p-1)&1, write p&1; slot = d % S.
  for (int phs = 0; phs < NPH; ++phs) {
    GruPhase P0{}, P1{};
    const int pprev = (phs + 1) & 1, pcur = phs & 1;
    int C = 0;
    for (int d = 0; d < DS; ++d) {
      int t = phs - SKEW * d;
      if (t < 0 || t > 12) continue;
      int c = C++;
      P0.a1off[c] = (unsigned)((d + t) * BB * YP);          // token slot d+t
      P0.hoff[c]  = (unsigned)((pprev * S + d % S) * BB * HH);
      P0.ooff[c]  = (unsigned)((pcur * S + d % S) * BB * HH);
      if (t == 0) P0.zmask |= 1 << c;
      P1.a1off[c] = P0.ooff[c];   // L1 input = L0 output of this phase
      P1.hoff[c]  = P0.hoff[c];
      P1.ooff[c]  = P0.ooff[c];
    }
    P0.ncells = P1.ncells = C;
    P1.zmask = P0.zmask;
    const dim3 grid(8, C * 8);    // x = 8 col-groups (64c), y = 128-row tiles
    gru3<YP / 32><<<grid, 256, 0, stream>>>(tokh, tokl, YP, W0h, W0l, b_ih0,
                                            h0h, h0l, Wh0h, Wh0l, b_hh0,
                                            h0h, h0l, P0);
    gru3<HH / 32><<<grid, 256, 0, stream>>>(h0h, h0l, HH, Wi1h, Wi1l, b_ih1,
                                            h1h, h1l, Wh1h, Wh1l, b_hh1,
                                            h1h, h1l, P1);
    // decode step d finishes at phase 12 + SKEW*d: project + feed token 13+d
    if (phs >= 12 && (phs - 12) % SKEW == 0) {
      const int d = (phs - 12) / SKEW;
      const size_t hoff = (size_t)(pcur * S + d % S) * BB * HH;
      out_v<<<(BB * YY + 255) / 256, 256, 0, stream>>>(
          h1h + hoff, h1l + hoff, W_out, b_out, res,
          tokh + (size_t)(13 + d) * BB * YP, tokl + (size_t)(13 + d) * BB * YP,
          outp, d);
    }
  }
}